// Round 4
// baseline (446.519 us; speedup 1.0000x reference)
//
#include <hip/hip_runtime.h>
#include <math.h>

#define N_NODES 100000
#define N_EDGES 1600000
#define N_GRAPHS 64

// ordered-uint encode for float atomicMax (monotone bijection)
__device__ __forceinline__ unsigned f2o(float f) {
    unsigned u = __float_as_uint(f);
    return (u & 0x80000000u) ? ~u : (u | 0x80000000u);
}
__device__ __forceinline__ float o2f(unsigned u) {
    return (u & 0x80000000u) ? __uint_as_float(u & 0x7fffffffu) : __uint_as_float(~u);
}

// ---------------- degree count + per-edge slot ----------------
__global__ __launch_bounds__(256) void deg_kernel(const int* __restrict__ dst, int* __restrict__ cnt,
                                                  int* __restrict__ pos) {
    int e = blockIdx.x * 256 + threadIdx.x;
    if (e < N_EDGES) pos[e] = atomicAdd(&cnt[dst[e]], 1);
}

// ---------------- dis + row allocation (wave scan) ----------------
__global__ __launch_bounds__(256) void alloc_kernel(const int* __restrict__ cnt,
                                                    float* __restrict__ dis, int* __restrict__ rowptr,
                                                    int* __restrict__ total) {
    int i = blockIdx.x * 256 + threadIdx.x;
    int c = (i < N_NODES) ? cnt[i] : 0;
    if (i < N_NODES) dis[i] = rsqrtf((float)(c + 1));
    int lane = threadIdx.x & 63;
    int s = c;
    #pragma unroll
    for (int o = 1; o < 64; o <<= 1) {
        int v = __shfl_up(s, o, 64);
        if (lane >= o) s += v;
    }
    int wtot = __shfl(s, 63, 64);
    int base = 0;
    if (lane == 0) base = atomicAdd(total, wtot);
    base = __shfl(base, 0, 64);
    if (i < N_NODES) rowptr[i] = base + s - c;   // exclusive within wave
}

// ---------------- CSR fill (no atomics; nt scatter store) ----------------
__global__ __launch_bounds__(256) void fill_kernel(const int* __restrict__ src, const int* __restrict__ dst,
                                                   const int* __restrict__ rowptr, const int* __restrict__ pos,
                                                   int* __restrict__ colb) {
    int e = blockIdx.x * 256 + threadIdx.x;
    if (e >= N_EDGES) return;
    __builtin_nontemporal_store(src[e], &colb[rowptr[dst[e]] + pos[e]]);
}

// ---------------- GEMM1: hs1 = dis * (x @ W1), [N,128]x[128,32] ----------------
__global__ __launch_bounds__(256) void gemm1_kernel(const float* __restrict__ x, const float* __restrict__ W1,
                                                    const float* __restrict__ dis, float* __restrict__ hs1) {
    __shared__ float xs[64][128];     // 32 KB
    __shared__ float wt[32][132];     // W1^T padded
    int tid = threadIdx.x;
    int r0 = blockIdx.x * 64;
    for (int idx = tid; idx < 128 * 32; idx += 256) {
        int k = idx >> 5, j = idx & 31;
        wt[j][k] = W1[idx];
    }
    for (int idx = tid; idx < 64 * 32; idx += 256) {
        int r = idx >> 5, kc = idx & 31;
        int gr = r0 + r;
        float4 v = (gr < N_NODES) ? ((const float4*)x)[(size_t)gr * 32 + kc] : make_float4(0.f, 0.f, 0.f, 0.f);
        *(float4*)&xs[r][kc * 4] = v;
    }
    __syncthreads();
    int j = tid & 31;
    int rr = tid >> 5;   // 0..7
    float acc[8];
    #pragma unroll
    for (int i = 0; i < 8; i++) acc[i] = 0.f;
    for (int kc = 0; kc < 128; kc += 4) {
        float4 wv = *(const float4*)&wt[j][kc];
        #pragma unroll
        for (int i = 0; i < 8; i++) {
            float4 xv = *(const float4*)&xs[rr + i * 8][kc];
            acc[i] += xv.x * wv.x + xv.y * wv.y + xv.z * wv.z + xv.w * wv.w;
        }
    }
    #pragma unroll
    for (int i = 0; i < 8; i++) {
        int gr = r0 + rr + i * 8;
        if (gr < N_NODES) hs1[(size_t)gr * 32 + j] = dis[gr] * acc[i];
    }
}

// ---------------- agg1, lane-parallel edges, pure per-wave (no LDS/sync):
//   t1[r] = dis[r] * lrelu(dis[r]*(sum_neigh hs1 + self) + b1)
__global__ __launch_bounds__(256) void agg1_kernel(const float* __restrict__ hs1, const int* __restrict__ colb,
                                                   const int* __restrict__ rowptr, const int* __restrict__ cnt,
                                                   const float* __restrict__ dis, const float* __restrict__ b1,
                                                   float* __restrict__ t1) {
    int tid = threadIdx.x;
    int wid = tid >> 6;
    int lane = tid & 63;
    int es = lane >> 3;   // edge slot 0..7
    int q = lane & 7;     // feature quad 0..7
    int r = blockIdx.x * 4 + wid;          // N_NODES % 4 == 0
    int start = rowptr[r];
    int n = cnt[r];
    float4 acc0 = make_float4(0.f, 0.f, 0.f, 0.f);
    float4 acc1 = acc0;
    if (es == 0) acc0 = *(const float4*)&hs1[(size_t)r * 32 + q * 4];   // self
    for (int k = 0; k < n; k += 16) {
        int e0 = k + es, e1 = k + 8 + es;
        if (e0 < n) {
            int c = colb[start + e0];
            float4 v = *(const float4*)&hs1[(size_t)c * 32 + q * 4];
            acc0.x += v.x; acc0.y += v.y; acc0.z += v.z; acc0.w += v.w;
        }
        if (e1 < n) {
            int c = colb[start + e1];
            float4 v = *(const float4*)&hs1[(size_t)c * 32 + q * 4];
            acc1.x += v.x; acc1.y += v.y; acc1.z += v.z; acc1.w += v.w;
        }
    }
    float4 a;
    a.x = acc0.x + acc1.x; a.y = acc0.y + acc1.y; a.z = acc0.z + acc1.z; a.w = acc0.w + acc1.w;
    #pragma unroll
    for (int m = 8; m < 64; m <<= 1) {
        a.x += __shfl_xor(a.x, m, 64);
        a.y += __shfl_xor(a.y, m, 64);
        a.z += __shfl_xor(a.z, m, 64);
        a.w += __shfl_xor(a.w, m, 64);
    }
    if (es == 0) {
        float4 bv = *(const float4*)&b1[q * 4];
        float dr = dis[r];
        float4 v;
        v.x = dr * a.x + bv.x; v.y = dr * a.y + bv.y; v.z = dr * a.z + bv.z; v.w = dr * a.w + bv.w;
        v.x = v.x > 0.f ? v.x : 0.1f * v.x;
        v.y = v.y > 0.f ? v.y : 0.1f * v.y;
        v.z = v.z > 0.f ? v.z : 0.1f * v.z;
        v.w = v.w > 0.f ? v.w : 0.1f * v.w;
        v.x *= dr; v.y *= dr; v.z *= dr; v.w *= dr;
        *(float4*)&t1[(size_t)r * 32 + q * 4] = v;   // 8 lanes x 16B = full 128B row
    }
}

// ---------------- agg2 in 32-dim space + post-GEMM W2 + fused max-pool:
//   agg[r] = dis[r]*(sum_neigh t1 + t1_self); out = agg @ W2 + b2 -> atomicMax pool
__global__ __launch_bounds__(256) void agg2_kernel(const float* __restrict__ t1, const int* __restrict__ colb,
                                                   const int* __restrict__ rowptr, const int* __restrict__ cnt,
                                                   const float* __restrict__ dis, const float* __restrict__ b2,
                                                   const float* __restrict__ W2, const int* __restrict__ batch,
                                                   unsigned* __restrict__ gbufu) {
    __shared__ float w2s[32][64];
    __shared__ float aggs[4][32];
    __shared__ float red[4][64];
    __shared__ int rg[4];
    int tid = threadIdx.x;
    for (int idx = tid; idx < 32 * 64; idx += 256) w2s[idx >> 6][idx & 63] = W2[idx];
    int wid = tid >> 6;
    int lane = tid & 63;
    int es = lane >> 3;   // edge slot 0..7
    int q = lane & 7;     // feature quad 0..7
    int r = blockIdx.x * 4 + wid;
    int start = rowptr[r];
    int n = cnt[r];
    float4 acc0 = make_float4(0.f, 0.f, 0.f, 0.f);
    float4 acc1 = acc0;
    if (es == 0) acc0 = *(const float4*)&t1[(size_t)r * 32 + q * 4];   // self
    for (int k = 0; k < n; k += 16) {
        int e0 = k + es, e1 = k + 8 + es;
        if (e0 < n) {
            int c = colb[start + e0];
            float4 v = *(const float4*)&t1[(size_t)c * 32 + q * 4];
            acc0.x += v.x; acc0.y += v.y; acc0.z += v.z; acc0.w += v.w;
        }
        if (e1 < n) {
            int c = colb[start + e1];
            float4 v = *(const float4*)&t1[(size_t)c * 32 + q * 4];
            acc1.x += v.x; acc1.y += v.y; acc1.z += v.z; acc1.w += v.w;
        }
    }
    float4 a;
    a.x = acc0.x + acc1.x; a.y = acc0.y + acc1.y; a.z = acc0.z + acc1.z; a.w = acc0.w + acc1.w;
    #pragma unroll
    for (int m = 8; m < 64; m <<= 1) {
        a.x += __shfl_xor(a.x, m, 64);
        a.y += __shfl_xor(a.y, m, 64);
        a.z += __shfl_xor(a.z, m, 64);
        a.w += __shfl_xor(a.w, m, 64);
    }
    if (es == 0) {
        float dr = dis[r];
        float4 v;
        v.x = dr * a.x; v.y = dr * a.y; v.z = dr * a.z; v.w = dr * a.w;
        *(float4*)&aggs[wid][q * 4] = v;
    }
    if (lane == 0) rg[wid] = batch[r];
    __syncthreads();
    // phase 2: out[j] = aggs[wid] . W2[:,j] + b2[j]
    int j = lane;
    float s = b2[j];
    #pragma unroll
    for (int k2 = 0; k2 < 32; k2++) s += aggs[wid][k2] * w2s[k2][j];   // aggs broadcast read
    red[wid][j] = s;
    __syncthreads();
    if (tid < 64) {
        int g0 = rg[0];
        bool uni = (rg[1] == g0) & (rg[2] == g0) & (rg[3] == g0);
        if (uni) {
            float m = fmaxf(fmaxf(red[0][tid], red[1][tid]), fmaxf(red[2][tid], red[3][tid]));
            atomicMax(&gbufu[g0 * 64 + tid], f2o(m));
        } else {
            #pragma unroll
            for (int w = 0; w < 4; w++) atomicMax(&gbufu[rg[w] * 64 + tid], f2o(red[w][tid]));
        }
    }
}

// ---------------- MLP head, single block ----------------
__global__ __launch_bounds__(256) void mlp_kernel(const unsigned* __restrict__ gbufu,
                                                  const float* __restrict__ Wl1, const float* __restrict__ bl1,
                                                  const float* __restrict__ Wl2, const float* __restrict__ bl2,
                                                  const float* __restrict__ Wl3, const float* __restrict__ bl3,
                                                  float* __restrict__ out) {
    __shared__ float A[64][64];
    __shared__ float B[64][128];
    int tid = threadIdx.x;
    for (int idx = tid; idx < 64 * 64; idx += 256) A[idx >> 6][idx & 63] = o2f(gbufu[idx]);
    __syncthreads();
    {
        int j = tid & 127;
        int rg = tid >> 7;
        float wc[64];
        #pragma unroll
        for (int k = 0; k < 64; k++) wc[k] = Wl1[k * 128 + j];
        float bj = bl1[j];
        for (int r = rg; r < 64; r += 2) {
            float acc = bj;
            #pragma unroll
            for (int kc = 0; kc < 64; kc += 4) {
                float4 av = *(const float4*)&A[r][kc];
                acc += av.x * wc[kc] + av.y * wc[kc + 1] + av.z * wc[kc + 2] + av.w * wc[kc + 3];
            }
            B[r][j] = acc > 0.f ? acc : 0.1f * acc;
        }
    }
    __syncthreads();
    {
        int j = tid & 63;
        int rg = tid >> 6;
        float wc[128];
        #pragma unroll
        for (int k = 0; k < 128; k++) wc[k] = Wl2[k * 64 + j];
        float bj = bl2[j];
        for (int r = rg; r < 64; r += 4) {
            float acc = bj;
            #pragma unroll
            for (int kc = 0; kc < 128; kc += 4) {
                float4 bv = *(const float4*)&B[r][kc];
                acc += bv.x * wc[kc] + bv.y * wc[kc + 1] + bv.z * wc[kc + 2] + bv.w * wc[kc + 3];
            }
            A[r][j] = acc > 0.f ? acc : 0.1f * acc;
        }
    }
    __syncthreads();
    if (tid < 64) {
        int r = tid;
        float acc = bl3[0];
        #pragma unroll
        for (int k = 0; k < 64; k++) acc += A[r][k] * Wl3[k];
        out[r] = acc;
    }
}

extern "C" void kernel_launch(void* const* d_in, const int* in_sizes, int n_in,
                              void* d_out, int out_size, void* d_ws, size_t ws_size,
                              hipStream_t stream) {
    (void)in_sizes; (void)n_in; (void)out_size; (void)ws_size;
    const float* x    = (const float*)d_in[0];
    const int*   edge = (const int*)d_in[1];
    const int*   batch= (const int*)d_in[2];
    const float* W1   = (const float*)d_in[3];
    const float* b1   = (const float*)d_in[4];
    const float* W2   = (const float*)d_in[5];
    const float* b2   = (const float*)d_in[6];
    const float* Wl1  = (const float*)d_in[7];
    const float* bl1  = (const float*)d_in[8];
    const float* Wl2  = (const float*)d_in[9];
    const float* bl2  = (const float*)d_in[10];
    const float* Wl3  = (const float*)d_in[11];
    const float* bl3  = (const float*)d_in[12];
    const int* srcp = edge;
    const int* dstp = edge + N_EDGES;

    // workspace layout: zeroed region first = cnt[N] + total[1] + gbufu[64*64] -> one memset
    char* ws = (char*)d_ws;
    int*      cnt   = (int*)ws;
    int*      total = cnt + N_NODES;
    unsigned* gbufu = (unsigned*)(total + 1);
    size_t zeroed = (size_t)(N_NODES + 1 + N_GRAPHS * 64) * 4;
    size_t off = (zeroed + 255) & ~(size_t)255;
    auto alloc = [&](size_t bytes) { char* p = ws + off; off = (off + bytes + 255) & ~(size_t)255; return p; };
    int*   pos    = (int*)alloc((size_t)N_EDGES * 4);
    int*   rowptr = (int*)alloc((size_t)N_NODES * 4);
    float* dis    = (float*)alloc((size_t)N_NODES * 4);
    int*   colb   = (int*)alloc((size_t)N_EDGES * 4);
    float* hs1    = (float*)alloc((size_t)N_NODES * 32 * 4);
    float* t1     = (float*)alloc((size_t)N_NODES * 32 * 4);

    hipMemsetAsync(ws, 0, zeroed, stream);

    deg_kernel  <<<(N_EDGES + 255) / 256, 256, 0, stream>>>(dstp, cnt, pos);
    alloc_kernel<<<(N_NODES + 255) / 256, 256, 0, stream>>>(cnt, dis, rowptr, total);
    fill_kernel <<<(N_EDGES + 255) / 256, 256, 0, stream>>>(srcp, dstp, rowptr, pos, colb);
    gemm1_kernel<<<(N_NODES + 63) / 64, 256, 0, stream>>>(x, W1, dis, hs1);
    agg1_kernel <<<N_NODES / 4, 256, 0, stream>>>(hs1, colb, rowptr, cnt, dis, b1, t1);
    agg2_kernel <<<N_NODES / 4, 256, 0, stream>>>(t1, colb, rowptr, cnt, dis, b2, W2, batch, gbufu);
    mlp_kernel  <<<1, 256, 0, stream>>>(gbufu, Wl1, bl1, Wl2, bl2, Wl3, bl3, (float*)d_out);
}

// Round 5
// 430.049 us; speedup vs baseline: 1.0383x; 1.0383x over previous
//
#include <hip/hip_runtime.h>
#include <math.h>

#define N_NODES 100000
#define N_EDGES 1600000
#define N_GRAPHS 64

// ordered-uint encode for float atomicMax (monotone bijection)
__device__ __forceinline__ unsigned f2o(float f) {
    unsigned u = __float_as_uint(f);
    return (u & 0x80000000u) ? ~u : (u | 0x80000000u);
}
__device__ __forceinline__ float o2f(unsigned u) {
    return (u & 0x80000000u) ? __uint_as_float(u & 0x7fffffffu) : __uint_as_float(~u);
}

// ---------------- degree count + per-edge slot ----------------
__global__ __launch_bounds__(256) void deg_kernel(const int* __restrict__ dst, int* __restrict__ cnt,
                                                  int* __restrict__ pos) {
    int e = blockIdx.x * 256 + threadIdx.x;
    if (e < N_EDGES) pos[e] = atomicAdd(&cnt[dst[e]], 1);
}

// ---------------- dis + row allocation (wave scan) ----------------
__global__ __launch_bounds__(256) void alloc_kernel(const int* __restrict__ cnt,
                                                    float* __restrict__ dis, int* __restrict__ rowptr,
                                                    int* __restrict__ total) {
    int i = blockIdx.x * 256 + threadIdx.x;
    int c = (i < N_NODES) ? cnt[i] : 0;
    if (i < N_NODES) dis[i] = rsqrtf((float)(c + 1));
    int lane = threadIdx.x & 63;
    int s = c;
    #pragma unroll
    for (int o = 1; o < 64; o <<= 1) {
        int v = __shfl_up(s, o, 64);
        if (lane >= o) s += v;
    }
    int wtot = __shfl(s, 63, 64);
    int base = 0;
    if (lane == 0) base = atomicAdd(total, wtot);
    base = __shfl(base, 0, 64);
    if (i < N_NODES) rowptr[i] = base + s - c;   // exclusive within wave
}

// ---------------- CSR fill (no atomics; nt scatter store) ----------------
__global__ __launch_bounds__(256) void fill_kernel(const int* __restrict__ src, const int* __restrict__ dst,
                                                   const int* __restrict__ rowptr, const int* __restrict__ pos,
                                                   int* __restrict__ colb) {
    int e = blockIdx.x * 256 + threadIdx.x;
    if (e >= N_EDGES) return;
    __builtin_nontemporal_store(src[e], &colb[rowptr[dst[e]] + pos[e]]);
}

// ---------------- GEMM1: hs1 = dis * (x @ W1), [N,128]x[128,32] ----------------
__global__ __launch_bounds__(256) void gemm1_kernel(const float* __restrict__ x, const float* __restrict__ W1,
                                                    const float* __restrict__ dis, float* __restrict__ hs1) {
    __shared__ float xs[64][128];     // 32 KB
    __shared__ float wt[32][132];     // W1^T padded
    int tid = threadIdx.x;
    int r0 = blockIdx.x * 64;
    for (int idx = tid; idx < 128 * 32; idx += 256) {
        int k = idx >> 5, j = idx & 31;
        wt[j][k] = W1[idx];
    }
    for (int idx = tid; idx < 64 * 32; idx += 256) {
        int r = idx >> 5, kc = idx & 31;
        int gr = r0 + r;
        float4 v = (gr < N_NODES) ? ((const float4*)x)[(size_t)gr * 32 + kc] : make_float4(0.f, 0.f, 0.f, 0.f);
        *(float4*)&xs[r][kc * 4] = v;
    }
    __syncthreads();
    int j = tid & 31;
    int rr = tid >> 5;   // 0..7
    float acc[8];
    #pragma unroll
    for (int i = 0; i < 8; i++) acc[i] = 0.f;
    for (int kc = 0; kc < 128; kc += 4) {
        float4 wv = *(const float4*)&wt[j][kc];
        #pragma unroll
        for (int i = 0; i < 8; i++) {
            float4 xv = *(const float4*)&xs[rr + i * 8][kc];
            acc[i] += xv.x * wv.x + xv.y * wv.y + xv.z * wv.z + xv.w * wv.w;
        }
    }
    #pragma unroll
    for (int i = 0; i < 8; i++) {
        int gr = r0 + rr + i * 8;
        if (gr < N_NODES) hs1[(size_t)gr * 32 + j] = dis[gr] * acc[i];
    }
}

// ---------------- agg1, lane-parallel edges, pure per-wave (no LDS/sync):
//   t1[r] = dis[r] * lrelu(dis[r]*(sum_neigh hs1 + self) + b1)
__global__ __launch_bounds__(256) void agg1_kernel(const float* __restrict__ hs1, const int* __restrict__ colb,
                                                   const int* __restrict__ rowptr, const int* __restrict__ cnt,
                                                   const float* __restrict__ dis, const float* __restrict__ b1,
                                                   float* __restrict__ t1) {
    int tid = threadIdx.x;
    int wid = tid >> 6;
    int lane = tid & 63;
    int es = lane >> 3;   // edge slot 0..7
    int q = lane & 7;     // feature quad 0..7
    int r = blockIdx.x * 4 + wid;          // N_NODES % 4 == 0
    int start = rowptr[r];
    int n = cnt[r];
    float4 acc0 = make_float4(0.f, 0.f, 0.f, 0.f);
    float4 acc1 = acc0;
    if (es == 0) acc0 = *(const float4*)&hs1[(size_t)r * 32 + q * 4];   // self
    for (int k = 0; k < n; k += 16) {
        int e0 = k + es, e1 = k + 8 + es;
        if (e0 < n) {
            int c = colb[start + e0];
            float4 v = *(const float4*)&hs1[(size_t)c * 32 + q * 4];
            acc0.x += v.x; acc0.y += v.y; acc0.z += v.z; acc0.w += v.w;
        }
        if (e1 < n) {
            int c = colb[start + e1];
            float4 v = *(const float4*)&hs1[(size_t)c * 32 + q * 4];
            acc1.x += v.x; acc1.y += v.y; acc1.z += v.z; acc1.w += v.w;
        }
    }
    float4 a;
    a.x = acc0.x + acc1.x; a.y = acc0.y + acc1.y; a.z = acc0.z + acc1.z; a.w = acc0.w + acc1.w;
    #pragma unroll
    for (int m = 8; m < 64; m <<= 1) {
        a.x += __shfl_xor(a.x, m, 64);
        a.y += __shfl_xor(a.y, m, 64);
        a.z += __shfl_xor(a.z, m, 64);
        a.w += __shfl_xor(a.w, m, 64);
    }
    if (es == 0) {
        float4 bv = *(const float4*)&b1[q * 4];
        float dr = dis[r];
        float4 v;
        v.x = dr * a.x + bv.x; v.y = dr * a.y + bv.y; v.z = dr * a.z + bv.z; v.w = dr * a.w + bv.w;
        v.x = v.x > 0.f ? v.x : 0.1f * v.x;
        v.y = v.y > 0.f ? v.y : 0.1f * v.y;
        v.z = v.z > 0.f ? v.z : 0.1f * v.z;
        v.w = v.w > 0.f ? v.w : 0.1f * v.w;
        v.x *= dr; v.y *= dr; v.z *= dr; v.w *= dr;
        *(float4*)&t1[(size_t)r * 32 + q * 4] = v;   // 8 lanes x 16B = full 128B row
    }
}

// ---------------- agg2 v3: 16 rows per wave, in-wave W2 GEMM, running-max pool
//   lane j holds W2 column j in registers + running max for feature j.
//   One 64-lane atomicMax per graph-segment per wave (~410k atomics vs 1.6M).
//   No LDS, no __syncthreads.
__global__ __launch_bounds__(256) void agg2_kernel(const float* __restrict__ t1, const int* __restrict__ colb,
                                                   const int* __restrict__ rowptr, const int* __restrict__ cnt,
                                                   const float* __restrict__ dis, const float* __restrict__ b2,
                                                   const float* __restrict__ W2, const int* __restrict__ batch,
                                                   unsigned* __restrict__ gbufu) {
    const int ROWS = 16;   // 100000 / 16 = 6250 waves exactly
    int tid = threadIdx.x;
    int wid = tid >> 6;
    int lane = tid & 63;
    int w = blockIdx.x * 4 + wid;          // global wave id
    int r0 = w * ROWS;
    if (r0 >= N_NODES) return;             // idle tail waves (no LDS/sync in kernel)
    // per-lane W2 column + bias
    float w2c[32];
    #pragma unroll
    for (int k = 0; k < 32; k++) w2c[k] = W2[k * 64 + lane];
    float bb = b2[lane];
    int es = lane >> 3;   // edge slot 0..7
    int q = lane & 7;     // feature quad 0..7
    float runmax = -INFINITY;
    int curg = batch[r0];
    for (int i = 0; i < ROWS; i++) {
        int r = r0 + i;
        int start = rowptr[r];
        int n = cnt[r];
        float4 acc0 = make_float4(0.f, 0.f, 0.f, 0.f);
        float4 acc1 = acc0;
        if (es == 0) acc0 = *(const float4*)&t1[(size_t)r * 32 + q * 4];   // self
        for (int k = 0; k < n; k += 16) {
            int e0 = k + es, e1 = k + 8 + es;
            if (e0 < n) {
                int c = colb[start + e0];
                float4 v = *(const float4*)&t1[(size_t)c * 32 + q * 4];
                acc0.x += v.x; acc0.y += v.y; acc0.z += v.z; acc0.w += v.w;
            }
            if (e1 < n) {
                int c = colb[start + e1];
                float4 v = *(const float4*)&t1[(size_t)c * 32 + q * 4];
                acc1.x += v.x; acc1.y += v.y; acc1.z += v.z; acc1.w += v.w;
            }
        }
        float4 a;
        a.x = acc0.x + acc1.x; a.y = acc0.y + acc1.y; a.z = acc0.z + acc1.z; a.w = acc0.w + acc1.w;
        #pragma unroll
        for (int m = 8; m < 64; m <<= 1) {
            a.x += __shfl_xor(a.x, m, 64);
            a.y += __shfl_xor(a.y, m, 64);
            a.z += __shfl_xor(a.z, m, 64);
            a.w += __shfl_xor(a.w, m, 64);
        }
        // after xor-butterfly every lane holds reduced quad for its q = lane&7:
        // agg_pre[k] lives on lane (k>>2) (q = k>>2, es = 0), component k&3.
        float dot = 0.f;
        #pragma unroll
        for (int k2 = 0; k2 < 32; k2++) {
            float av;
            switch (k2 & 3) {
                case 0: av = __shfl(a.x, k2 >> 2, 64); break;
                case 1: av = __shfl(a.y, k2 >> 2, 64); break;
                case 2: av = __shfl(a.z, k2 >> 2, 64); break;
                default: av = __shfl(a.w, k2 >> 2, 64); break;
            }
            dot += av * w2c[k2];
        }
        float s = fmaf(dis[r], dot, bb);   // out[r][lane]
        int g = batch[r];                  // uniform across wave
        if (g != curg) {
            atomicMax(&gbufu[curg * 64 + lane], f2o(runmax));
            runmax = -INFINITY;
            curg = g;
        }
        runmax = fmaxf(runmax, s);
    }
    atomicMax(&gbufu[curg * 64 + lane], f2o(runmax));
}

// ---------------- MLP head, single block ----------------
__global__ __launch_bounds__(256) void mlp_kernel(const unsigned* __restrict__ gbufu,
                                                  const float* __restrict__ Wl1, const float* __restrict__ bl1,
                                                  const float* __restrict__ Wl2, const float* __restrict__ bl2,
                                                  const float* __restrict__ Wl3, const float* __restrict__ bl3,
                                                  float* __restrict__ out) {
    __shared__ float A[64][64];
    __shared__ float B[64][128];
    int tid = threadIdx.x;
    for (int idx = tid; idx < 64 * 64; idx += 256) A[idx >> 6][idx & 63] = o2f(gbufu[idx]);
    __syncthreads();
    {
        int j = tid & 127;
        int rg = tid >> 7;
        float wc[64];
        #pragma unroll
        for (int k = 0; k < 64; k++) wc[k] = Wl1[k * 128 + j];
        float bj = bl1[j];
        for (int r = rg; r < 64; r += 2) {
            float acc = bj;
            #pragma unroll
            for (int kc = 0; kc < 64; kc += 4) {
                float4 av = *(const float4*)&A[r][kc];
                acc += av.x * wc[kc] + av.y * wc[kc + 1] + av.z * wc[kc + 2] + av.w * wc[kc + 3];
            }
            B[r][j] = acc > 0.f ? acc : 0.1f * acc;
        }
    }
    __syncthreads();
    {
        int j = tid & 63;
        int rg = tid >> 6;
        float wc[128];
        #pragma unroll
        for (int k = 0; k < 128; k++) wc[k] = Wl2[k * 64 + j];
        float bj = bl2[j];
        for (int r = rg; r < 64; r += 4) {
            float acc = bj;
            #pragma unroll
            for (int kc = 0; kc < 128; kc += 4) {
                float4 bv = *(const float4*)&B[r][kc];
                acc += bv.x * wc[kc] + bv.y * wc[kc + 1] + bv.z * wc[kc + 2] + bv.w * wc[kc + 3];
            }
            A[r][j] = acc > 0.f ? acc : 0.1f * acc;
        }
    }
    __syncthreads();
    if (tid < 64) {
        int r = tid;
        float acc = bl3[0];
        #pragma unroll
        for (int k = 0; k < 64; k++) acc += A[r][k] * Wl3[k];
        out[r] = acc;
    }
}

extern "C" void kernel_launch(void* const* d_in, const int* in_sizes, int n_in,
                              void* d_out, int out_size, void* d_ws, size_t ws_size,
                              hipStream_t stream) {
    (void)in_sizes; (void)n_in; (void)out_size; (void)ws_size;
    const float* x    = (const float*)d_in[0];
    const int*   edge = (const int*)d_in[1];
    const int*   batch= (const int*)d_in[2];
    const float* W1   = (const float*)d_in[3];
    const float* b1   = (const float*)d_in[4];
    const float* W2   = (const float*)d_in[5];
    const float* b2   = (const float*)d_in[6];
    const float* Wl1  = (const float*)d_in[7];
    const float* bl1  = (const float*)d_in[8];
    const float* Wl2  = (const float*)d_in[9];
    const float* bl2  = (const float*)d_in[10];
    const float* Wl3  = (const float*)d_in[11];
    const float* bl3  = (const float*)d_in[12];
    const int* srcp = edge;
    const int* dstp = edge + N_EDGES;

    // workspace layout: zeroed region first = cnt[N] + total[1] + gbufu[64*64] -> one memset
    char* ws = (char*)d_ws;
    int*      cnt   = (int*)ws;
    int*      total = cnt + N_NODES;
    unsigned* gbufu = (unsigned*)(total + 1);
    size_t zeroed = (size_t)(N_NODES + 1 + N_GRAPHS * 64) * 4;
    size_t off = (zeroed + 255) & ~(size_t)255;
    auto alloc = [&](size_t bytes) { char* p = ws + off; off = (off + bytes + 255) & ~(size_t)255; return p; };
    int*   pos    = (int*)alloc((size_t)N_EDGES * 4);
    int*   rowptr = (int*)alloc((size_t)N_NODES * 4);
    float* dis    = (float*)alloc((size_t)N_NODES * 4);
    int*   colb   = (int*)alloc((size_t)N_EDGES * 4);
    float* hs1    = (float*)alloc((size_t)N_NODES * 32 * 4);
    float* t1     = (float*)alloc((size_t)N_NODES * 32 * 4);

    hipMemsetAsync(ws, 0, zeroed, stream);

    deg_kernel  <<<(N_EDGES + 255) / 256, 256, 0, stream>>>(dstp, cnt, pos);
    alloc_kernel<<<(N_NODES + 255) / 256, 256, 0, stream>>>(cnt, dis, rowptr, total);
    fill_kernel <<<(N_EDGES + 255) / 256, 256, 0, stream>>>(srcp, dstp, rowptr, pos, colb);
    gemm1_kernel<<<(N_NODES + 63) / 64, 256, 0, stream>>>(x, W1, dis, hs1);
    agg1_kernel <<<N_NODES / 4, 256, 0, stream>>>(hs1, colb, rowptr, cnt, dis, b1, t1);
    // 6250 waves of 16 rows each -> 1563 blocks (tail waves exit early)
    agg2_kernel <<<(6250 + 3) / 4, 256, 0, stream>>>(t1, colb, rowptr, cnt, dis, b2, W2, batch, gbufu);
    mlp_kernel  <<<1, 256, 0, stream>>>(gbufu, Wl1, bl1, Wl2, bl2, Wl3, bl3, (float*)d_out);
}

// Round 6
// 417.188 us; speedup vs baseline: 1.0703x; 1.0308x over previous
//
#include <hip/hip_runtime.h>
#include <math.h>

#define N_NODES 100000
#define N_EDGES 1600000
#define N_GRAPHS 64

// ordered-uint encode for float atomicMax (monotone bijection)
__device__ __forceinline__ unsigned f2o(float f) {
    unsigned u = __float_as_uint(f);
    return (u & 0x80000000u) ? ~u : (u | 0x80000000u);
}
__device__ __forceinline__ float o2f(unsigned u) {
    return (u & 0x80000000u) ? __uint_as_float(u & 0x7fffffffu) : __uint_as_float(~u);
}

// ---------------- degree count + per-edge slot ----------------
__global__ __launch_bounds__(256) void deg_kernel(const int* __restrict__ dst, int* __restrict__ cnt,
                                                  int* __restrict__ pos) {
    int e = blockIdx.x * 256 + threadIdx.x;
    if (e < N_EDGES) pos[e] = atomicAdd(&cnt[dst[e]], 1);
}

// ---------------- dis + row allocation (wave scan) ----------------
__global__ __launch_bounds__(256) void alloc_kernel(const int* __restrict__ cnt,
                                                    float* __restrict__ dis, int* __restrict__ rowptr,
                                                    int* __restrict__ total) {
    int i = blockIdx.x * 256 + threadIdx.x;
    int c = (i < N_NODES) ? cnt[i] : 0;
    if (i < N_NODES) dis[i] = rsqrtf((float)(c + 1));
    int lane = threadIdx.x & 63;
    int s = c;
    #pragma unroll
    for (int o = 1; o < 64; o <<= 1) {
        int v = __shfl_up(s, o, 64);
        if (lane >= o) s += v;
    }
    int wtot = __shfl(s, 63, 64);
    int base = 0;
    if (lane == 0) base = atomicAdd(total, wtot);
    base = __shfl(base, 0, 64);
    if (i < N_NODES) rowptr[i] = base + s - c;   // exclusive within wave
}

// ---------------- CSR fill (no atomics; nt scatter store) ----------------
__global__ __launch_bounds__(256) void fill_kernel(const int* __restrict__ src, const int* __restrict__ dst,
                                                   const int* __restrict__ rowptr, const int* __restrict__ pos,
                                                   int* __restrict__ colb) {
    int e = blockIdx.x * 256 + threadIdx.x;
    if (e >= N_EDGES) return;
    __builtin_nontemporal_store(src[e], &colb[rowptr[dst[e]] + pos[e]]);
}

// ---------------- GEMM1: hs1 = dis * (x @ W1), [N,128]x[128,32] ----------------
__global__ __launch_bounds__(256) void gemm1_kernel(const float* __restrict__ x, const float* __restrict__ W1,
                                                    const float* __restrict__ dis, float* __restrict__ hs1) {
    __shared__ float xs[64][128];     // 32 KB
    __shared__ float wt[32][132];     // W1^T padded
    int tid = threadIdx.x;
    int r0 = blockIdx.x * 64;
    for (int idx = tid; idx < 128 * 32; idx += 256) {
        int k = idx >> 5, j = idx & 31;
        wt[j][k] = W1[idx];
    }
    for (int idx = tid; idx < 64 * 32; idx += 256) {
        int r = idx >> 5, kc = idx & 31;
        int gr = r0 + r;
        float4 v = (gr < N_NODES) ? ((const float4*)x)[(size_t)gr * 32 + kc] : make_float4(0.f, 0.f, 0.f, 0.f);
        *(float4*)&xs[r][kc * 4] = v;
    }
    __syncthreads();
    int j = tid & 31;
    int rr = tid >> 5;   // 0..7
    float acc[8];
    #pragma unroll
    for (int i = 0; i < 8; i++) acc[i] = 0.f;
    for (int kc = 0; kc < 128; kc += 4) {
        float4 wv = *(const float4*)&wt[j][kc];
        #pragma unroll
        for (int i = 0; i < 8; i++) {
            float4 xv = *(const float4*)&xs[rr + i * 8][kc];
            acc[i] += xv.x * wv.x + xv.y * wv.y + xv.z * wv.z + xv.w * wv.w;
        }
    }
    #pragma unroll
    for (int i = 0; i < 8; i++) {
        int gr = r0 + rr + i * 8;
        if (gr < N_NODES) hs1[(size_t)gr * 32 + j] = dis[gr] * acc[i];
    }
}

// ---------------- agg1, lane-parallel edges, pure per-wave (no LDS/sync):
//   t1[r] = dis[r] * lrelu(dis[r]*(sum_neigh hs1 + self) + b1)
__global__ __launch_bounds__(256) void agg1_kernel(const float* __restrict__ hs1, const int* __restrict__ colb,
                                                   const int* __restrict__ rowptr, const int* __restrict__ cnt,
                                                   const float* __restrict__ dis, const float* __restrict__ b1,
                                                   float* __restrict__ t1) {
    int tid = threadIdx.x;
    int wid = tid >> 6;
    int lane = tid & 63;
    int es = lane >> 3;   // edge slot 0..7
    int q = lane & 7;     // feature quad 0..7
    int r = blockIdx.x * 4 + wid;          // N_NODES % 4 == 0
    int start = rowptr[r];
    int n = cnt[r];
    float4 acc0 = make_float4(0.f, 0.f, 0.f, 0.f);
    float4 acc1 = acc0;
    if (es == 0) acc0 = *(const float4*)&hs1[(size_t)r * 32 + q * 4];   // self
    for (int k = 0; k < n; k += 16) {
        int e0 = k + es, e1 = k + 8 + es;
        if (e0 < n) {
            int c = colb[start + e0];
            float4 v = *(const float4*)&hs1[(size_t)c * 32 + q * 4];
            acc0.x += v.x; acc0.y += v.y; acc0.z += v.z; acc0.w += v.w;
        }
        if (e1 < n) {
            int c = colb[start + e1];
            float4 v = *(const float4*)&hs1[(size_t)c * 32 + q * 4];
            acc1.x += v.x; acc1.y += v.y; acc1.z += v.z; acc1.w += v.w;
        }
    }
    float4 a;
    a.x = acc0.x + acc1.x; a.y = acc0.y + acc1.y; a.z = acc0.z + acc1.z; a.w = acc0.w + acc1.w;
    #pragma unroll
    for (int m = 8; m < 64; m <<= 1) {
        a.x += __shfl_xor(a.x, m, 64);
        a.y += __shfl_xor(a.y, m, 64);
        a.z += __shfl_xor(a.z, m, 64);
        a.w += __shfl_xor(a.w, m, 64);
    }
    if (es == 0) {
        float4 bv = *(const float4*)&b1[q * 4];
        float dr = dis[r];
        float4 v;
        v.x = dr * a.x + bv.x; v.y = dr * a.y + bv.y; v.z = dr * a.z + bv.z; v.w = dr * a.w + bv.w;
        v.x = v.x > 0.f ? v.x : 0.1f * v.x;
        v.y = v.y > 0.f ? v.y : 0.1f * v.y;
        v.z = v.z > 0.f ? v.z : 0.1f * v.z;
        v.w = v.w > 0.f ? v.w : 0.1f * v.w;
        v.x *= dr; v.y *= dr; v.z *= dr; v.w *= dr;
        *(float4*)&t1[(size_t)r * 32 + q * 4] = v;   // 8 lanes x 16B = full 128B row
    }
}

// ---------------- agg2 v4: 8 rows/wave, 2-stage software pipeline, in-wave W2,
//   per-block atomic flush. Pre-issues next row's 5 gathers (self + 4 edge
//   slots covering 32 edges) before reducing current row, hiding L2/L3 latency
//   under the shfl chain. 12500 waves = 3125 blocks exactly (uniform barrier).
__global__ __launch_bounds__(256) void agg2_kernel(const float* __restrict__ t1, const int* __restrict__ colb,
                                                   const int* __restrict__ rowptr, const int* __restrict__ cnt,
                                                   const float* __restrict__ dis, const float* __restrict__ b2,
                                                   const float* __restrict__ W2, const int* __restrict__ batch,
                                                   unsigned* __restrict__ gbufu) {
    const int ROWS = 8;
    __shared__ float red[4][64];
    __shared__ int rg[4];
    int tid = threadIdx.x;
    int wid = tid >> 6;
    int lane = tid & 63;
    int es = lane >> 3;   // edge slot 0..7
    int q = lane & 7;     // feature quad 0..7
    int w = blockIdx.x * 4 + wid;          // 12500 waves exactly
    int r0 = w * ROWS;
    // per-lane W2 column + bias
    float w2c[32];
    #pragma unroll
    for (int k = 0; k < 32; k++) w2c[k] = W2[k * 64 + lane];
    float bb = b2[lane];
    float runmax = -INFINITY;
    int curg = batch[r0];

    const float4 z = make_float4(0.f, 0.f, 0.f, 0.f);
    // pre-issue row r0
    int st = rowptr[r0];
    int n = cnt[r0];
    float4 pS = z, p0 = z, p1 = z, p2 = z, p3 = z;
    if (es == 0) pS = *(const float4*)&t1[(size_t)r0 * 32 + q * 4];
    {
        int e0 = es, e1 = 8 + es, e2 = 16 + es, e3 = 24 + es;
        if (e0 < n) p0 = *(const float4*)&t1[(size_t)colb[st + e0] * 32 + q * 4];
        if (e1 < n) p1 = *(const float4*)&t1[(size_t)colb[st + e1] * 32 + q * 4];
        if (e2 < n) p2 = *(const float4*)&t1[(size_t)colb[st + e2] * 32 + q * 4];
        if (e3 < n) p3 = *(const float4*)&t1[(size_t)colb[st + e3] * 32 + q * 4];
    }
    for (int i = 0; i < ROWS; i++) {
        int r = r0 + i;
        int stA = st, nA = n;
        float4 s = pS, a0 = p0, a1 = p1, a2 = p2, a3 = p3;
        // pre-issue row r+1 before consuming row r
        pS = z; p0 = z; p1 = z; p2 = z; p3 = z;
        if (i + 1 < ROWS) {
            int rn = r + 1;
            st = rowptr[rn];
            n = cnt[rn];
            if (es == 0) pS = *(const float4*)&t1[(size_t)rn * 32 + q * 4];
            int e0 = es, e1 = 8 + es, e2 = 16 + es, e3 = 24 + es;
            if (e0 < n) p0 = *(const float4*)&t1[(size_t)colb[st + e0] * 32 + q * 4];
            if (e1 < n) p1 = *(const float4*)&t1[(size_t)colb[st + e1] * 32 + q * 4];
            if (e2 < n) p2 = *(const float4*)&t1[(size_t)colb[st + e2] * 32 + q * 4];
            if (e3 < n) p3 = *(const float4*)&t1[(size_t)colb[st + e3] * 32 + q * 4];
        }
        // reduce row r (waits only on row r's loads; next row's stay in flight)
        float4 a;
        a.x = (s.x + (a0.x + a1.x)) + (a2.x + a3.x);
        a.y = (s.y + (a0.y + a1.y)) + (a2.y + a3.y);
        a.z = (s.z + (a0.z + a1.z)) + (a2.z + a3.z);
        a.w = (s.w + (a0.w + a1.w)) + (a2.w + a3.w);
        // rare tail: degree > 32 (P ~ 1e-4 at Poisson(16))
        for (int k = 32; k < nA; k += 16) {
            int e0 = k + es, e1 = k + 8 + es;
            if (e0 < nA) {
                int c = colb[stA + e0];
                float4 v = *(const float4*)&t1[(size_t)c * 32 + q * 4];
                a.x += v.x; a.y += v.y; a.z += v.z; a.w += v.w;
            }
            if (e1 < nA) {
                int c = colb[stA + e1];
                float4 v = *(const float4*)&t1[(size_t)c * 32 + q * 4];
                a.x += v.x; a.y += v.y; a.z += v.z; a.w += v.w;
            }
        }
        #pragma unroll
        for (int m = 8; m < 64; m <<= 1) {
            a.x += __shfl_xor(a.x, m, 64);
            a.y += __shfl_xor(a.y, m, 64);
            a.z += __shfl_xor(a.z, m, 64);
            a.w += __shfl_xor(a.w, m, 64);
        }
        // agg_pre[k] lives on lane (k>>2), component k&3
        float dot = 0.f;
        #pragma unroll
        for (int k2 = 0; k2 < 32; k2++) {
            float av;
            switch (k2 & 3) {
                case 0: av = __shfl(a.x, k2 >> 2, 64); break;
                case 1: av = __shfl(a.y, k2 >> 2, 64); break;
                case 2: av = __shfl(a.z, k2 >> 2, 64); break;
                default: av = __shfl(a.w, k2 >> 2, 64); break;
            }
            dot += av * w2c[k2];
        }
        float sOut = fmaf(dis[r], dot, bb);   // out[r][lane]
        int g = batch[r];                     // uniform across wave
        if (g != curg) {                      // rare: ~63 boundaries / 12500 waves
            atomicMax(&gbufu[curg * 64 + lane], f2o(runmax));
            runmax = -INFINITY;
            curg = g;
        }
        runmax = fmaxf(runmax, sOut);
    }
    // block-level flush: one atomic per block in the common case
    red[wid][lane] = runmax;
    if (lane == 0) rg[wid] = curg;
    __syncthreads();
    if (tid < 64) {
        int g0 = rg[0];
        bool uni = (rg[1] == g0) & (rg[2] == g0) & (rg[3] == g0);
        if (uni) {
            float m = fmaxf(fmaxf(red[0][tid], red[1][tid]), fmaxf(red[2][tid], red[3][tid]));
            atomicMax(&gbufu[g0 * 64 + tid], f2o(m));
        } else {
            #pragma unroll
            for (int v = 0; v < 4; v++) atomicMax(&gbufu[rg[v] * 64 + tid], f2o(red[v][tid]));
        }
    }
}

// ---------------- MLP head, single block ----------------
__global__ __launch_bounds__(256) void mlp_kernel(const unsigned* __restrict__ gbufu,
                                                  const float* __restrict__ Wl1, const float* __restrict__ bl1,
                                                  const float* __restrict__ Wl2, const float* __restrict__ bl2,
                                                  const float* __restrict__ Wl3, const float* __restrict__ bl3,
                                                  float* __restrict__ out) {
    __shared__ float A[64][64];
    __shared__ float B[64][128];
    int tid = threadIdx.x;
    for (int idx = tid; idx < 64 * 64; idx += 256) A[idx >> 6][idx & 63] = o2f(gbufu[idx]);
    __syncthreads();
    {
        int j = tid & 127;
        int rg = tid >> 7;
        float wc[64];
        #pragma unroll
        for (int k = 0; k < 64; k++) wc[k] = Wl1[k * 128 + j];
        float bj = bl1[j];
        for (int r = rg; r < 64; r += 2) {
            float acc = bj;
            #pragma unroll
            for (int kc = 0; kc < 64; kc += 4) {
                float4 av = *(const float4*)&A[r][kc];
                acc += av.x * wc[kc] + av.y * wc[kc + 1] + av.z * wc[kc + 2] + av.w * wc[kc + 3];
            }
            B[r][j] = acc > 0.f ? acc : 0.1f * acc;
        }
    }
    __syncthreads();
    {
        int j = tid & 63;
        int rg = tid >> 6;
        float wc[128];
        #pragma unroll
        for (int k = 0; k < 128; k++) wc[k] = Wl2[k * 64 + j];
        float bj = bl2[j];
        for (int r = rg; r < 64; r += 4) {
            float acc = bj;
            #pragma unroll
            for (int kc = 0; kc < 128; kc += 4) {
                float4 bv = *(const float4*)&B[r][kc];
                acc += bv.x * wc[kc] + bv.y * wc[kc + 1] + bv.z * wc[kc + 2] + bv.w * wc[kc + 3];
            }
            A[r][j] = acc > 0.f ? acc : 0.1f * acc;
        }
    }
    __syncthreads();
    if (tid < 64) {
        int r = tid;
        float acc = bl3[0];
        #pragma unroll
        for (int k = 0; k < 64; k++) acc += A[r][k] * Wl3[k];
        out[r] = acc;
    }
}

extern "C" void kernel_launch(void* const* d_in, const int* in_sizes, int n_in,
                              void* d_out, int out_size, void* d_ws, size_t ws_size,
                              hipStream_t stream) {
    (void)in_sizes; (void)n_in; (void)out_size; (void)ws_size;
    const float* x    = (const float*)d_in[0];
    const int*   edge = (const int*)d_in[1];
    const int*   batch= (const int*)d_in[2];
    const float* W1   = (const float*)d_in[3];
    const float* b1   = (const float*)d_in[4];
    const float* W2   = (const float*)d_in[5];
    const float* b2   = (const float*)d_in[6];
    const float* Wl1  = (const float*)d_in[7];
    const float* bl1  = (const float*)d_in[8];
    const float* Wl2  = (const float*)d_in[9];
    const float* bl2  = (const float*)d_in[10];
    const float* Wl3  = (const float*)d_in[11];
    const float* bl3  = (const float*)d_in[12];
    const int* srcp = edge;
    const int* dstp = edge + N_EDGES;

    // workspace layout: zeroed region first = cnt[N] + total[1] + gbufu[64*64] -> one memset
    char* ws = (char*)d_ws;
    int*      cnt   = (int*)ws;
    int*      total = cnt + N_NODES;
    unsigned* gbufu = (unsigned*)(total + 1);
    size_t zeroed = (size_t)(N_NODES + 1 + N_GRAPHS * 64) * 4;
    size_t off = (zeroed + 255) & ~(size_t)255;
    auto alloc = [&](size_t bytes) { char* p = ws + off; off = (off + bytes + 255) & ~(size_t)255; return p; };
    int*   pos    = (int*)alloc((size_t)N_EDGES * 4);
    int*   rowptr = (int*)alloc((size_t)N_NODES * 4);
    float* dis    = (float*)alloc((size_t)N_NODES * 4);
    int*   colb   = (int*)alloc((size_t)N_EDGES * 4);
    float* hs1    = (float*)alloc((size_t)N_NODES * 32 * 4);
    float* t1     = (float*)alloc((size_t)N_NODES * 32 * 4);

    hipMemsetAsync(ws, 0, zeroed, stream);

    deg_kernel  <<<(N_EDGES + 255) / 256, 256, 0, stream>>>(dstp, cnt, pos);
    alloc_kernel<<<(N_NODES + 255) / 256, 256, 0, stream>>>(cnt, dis, rowptr, total);
    fill_kernel <<<(N_EDGES + 255) / 256, 256, 0, stream>>>(srcp, dstp, rowptr, pos, colb);
    gemm1_kernel<<<(N_NODES + 63) / 64, 256, 0, stream>>>(x, W1, dis, hs1);
    agg1_kernel <<<N_NODES / 4, 256, 0, stream>>>(hs1, colb, rowptr, cnt, dis, b1, t1);
    // 12500 waves of 8 rows each -> 3125 blocks exactly
    agg2_kernel <<<3125, 256, 0, stream>>>(t1, colb, rowptr, cnt, dis, b2, W2, batch, gbufu);
    mlp_kernel  <<<1, 256, 0, stream>>>(gbufu, Wl1, bl1, Wl2, bl2, Wl3, bl3, (float*)d_out);
}

// Round 7
// 402.905 us; speedup vs baseline: 1.1082x; 1.0354x over previous
//
#include <hip/hip_runtime.h>
#include <hip/hip_fp16.h>
#include <math.h>

#define N_NODES 100000
#define N_EDGES 1600000
#define N_GRAPHS 64

// ordered-uint encode for float atomicMax (monotone bijection)
__device__ __forceinline__ unsigned f2o(float f) {
    unsigned u = __float_as_uint(f);
    return (u & 0x80000000u) ? ~u : (u | 0x80000000u);
}
__device__ __forceinline__ float o2f(unsigned u) {
    return (u & 0x80000000u) ? __uint_as_float(u & 0x7fffffffu) : __uint_as_float(~u);
}

// 8B load of 4 fp16 -> float4
__device__ __forceinline__ float4 cvt8(float2 raw) {
    __half2 h0 = ((const __half2*)&raw)[0];
    __half2 h1 = ((const __half2*)&raw)[1];
    float2 f0 = __half22float2(h0);
    float2 f1 = __half22float2(h1);
    return make_float4(f0.x, f0.y, f1.x, f1.y);
}
__device__ __forceinline__ float4 loadh8(const __half* p) {
    return cvt8(*(const float2*)p);
}
__device__ __forceinline__ void storeh8(__half* p, float4 v) {
    __half2 o0 = __floats2half2_rn(v.x, v.y);
    __half2 o1 = __floats2half2_rn(v.z, v.w);
    float2 ow;
    ((__half2*)&ow)[0] = o0;
    ((__half2*)&ow)[1] = o1;
    *(float2*)p = ow;
}

// ---------------- degree count + per-edge slot ----------------
__global__ __launch_bounds__(256) void deg_kernel(const int* __restrict__ dst, int* __restrict__ cnt,
                                                  int* __restrict__ pos) {
    int e = blockIdx.x * 256 + threadIdx.x;
    if (e < N_EDGES) pos[e] = atomicAdd(&cnt[dst[e]], 1);
}

// ---------------- dis + row allocation (wave scan) ----------------
__global__ __launch_bounds__(256) void alloc_kernel(const int* __restrict__ cnt,
                                                    float* __restrict__ dis, int* __restrict__ rowptr,
                                                    int* __restrict__ total) {
    int i = blockIdx.x * 256 + threadIdx.x;
    int c = (i < N_NODES) ? cnt[i] : 0;
    if (i < N_NODES) dis[i] = rsqrtf((float)(c + 1));
    int lane = threadIdx.x & 63;
    int s = c;
    #pragma unroll
    for (int o = 1; o < 64; o <<= 1) {
        int v = __shfl_up(s, o, 64);
        if (lane >= o) s += v;
    }
    int wtot = __shfl(s, 63, 64);
    int base = 0;
    if (lane == 0) base = atomicAdd(total, wtot);
    base = __shfl(base, 0, 64);
    if (i < N_NODES) rowptr[i] = base + s - c;   // exclusive within wave
}

// ---------------- CSR fill (no atomics; nt scatter store) ----------------
__global__ __launch_bounds__(256) void fill_kernel(const int* __restrict__ src, const int* __restrict__ dst,
                                                   const int* __restrict__ rowptr, const int* __restrict__ pos,
                                                   int* __restrict__ colb) {
    int e = blockIdx.x * 256 + threadIdx.x;
    if (e >= N_EDGES) return;
    __builtin_nontemporal_store(src[e], &colb[rowptr[dst[e]] + pos[e]]);
}

// ---------------- GEMM1: hs1h = fp16(dis * (x @ W1)), [N,128]x[128,32] ----------------
__global__ __launch_bounds__(256) void gemm1_kernel(const float* __restrict__ x, const float* __restrict__ W1,
                                                    const float* __restrict__ dis, __half* __restrict__ hs1h) {
    __shared__ float xs[64][128];     // 32 KB
    __shared__ float wt[32][132];     // W1^T padded
    int tid = threadIdx.x;
    int r0 = blockIdx.x * 64;
    for (int idx = tid; idx < 128 * 32; idx += 256) {
        int k = idx >> 5, j = idx & 31;
        wt[j][k] = W1[idx];
    }
    for (int idx = tid; idx < 64 * 32; idx += 256) {
        int r = idx >> 5, kc = idx & 31;
        int gr = r0 + r;
        float4 v = (gr < N_NODES) ? ((const float4*)x)[(size_t)gr * 32 + kc] : make_float4(0.f, 0.f, 0.f, 0.f);
        *(float4*)&xs[r][kc * 4] = v;
    }
    __syncthreads();
    int j = tid & 31;
    int rr = tid >> 5;   // 0..7
    float acc[8];
    #pragma unroll
    for (int i = 0; i < 8; i++) acc[i] = 0.f;
    for (int kc = 0; kc < 128; kc += 4) {
        float4 wv = *(const float4*)&wt[j][kc];
        #pragma unroll
        for (int i = 0; i < 8; i++) {
            float4 xv = *(const float4*)&xs[rr + i * 8][kc];
            acc[i] += xv.x * wv.x + xv.y * wv.y + xv.z * wv.z + xv.w * wv.w;
        }
    }
    #pragma unroll
    for (int i = 0; i < 8; i++) {
        int gr = r0 + rr + i * 8;
        if (gr < N_NODES) hs1h[(size_t)gr * 32 + j] = __float2half_rn(dis[gr] * acc[i]);
    }
}

// ---------------- agg1, lane-parallel edges over fp16 rows (64B = 1 line/row):
//   t1h[r] = fp16( dis[r] * lrelu(dis[r]*(sum_neigh hs1 + self) + b1) )
__global__ __launch_bounds__(256) void agg1_kernel(const __half* __restrict__ hs1h, const int* __restrict__ colb,
                                                   const int* __restrict__ rowptr, const int* __restrict__ cnt,
                                                   const float* __restrict__ dis, const float* __restrict__ b1,
                                                   __half* __restrict__ t1h) {
    int tid = threadIdx.x;
    int wid = tid >> 6;
    int lane = tid & 63;
    int es = lane >> 3;   // edge slot 0..7
    int q = lane & 7;     // feature quad 0..7
    int r = blockIdx.x * 4 + wid;          // N_NODES % 4 == 0
    int start = rowptr[r];
    int n = cnt[r];
    float4 acc0 = make_float4(0.f, 0.f, 0.f, 0.f);
    float4 acc1 = acc0;
    if (es == 0) acc0 = loadh8(hs1h + (size_t)r * 32 + q * 4);   // self
    for (int k = 0; k < n; k += 16) {
        int e0 = k + es, e1 = k + 8 + es;
        if (e0 < n) {
            int c = colb[start + e0];
            float4 v = loadh8(hs1h + (size_t)c * 32 + q * 4);
            acc0.x += v.x; acc0.y += v.y; acc0.z += v.z; acc0.w += v.w;
        }
        if (e1 < n) {
            int c = colb[start + e1];
            float4 v = loadh8(hs1h + (size_t)c * 32 + q * 4);
            acc1.x += v.x; acc1.y += v.y; acc1.z += v.z; acc1.w += v.w;
        }
    }
    float4 a;
    a.x = acc0.x + acc1.x; a.y = acc0.y + acc1.y; a.z = acc0.z + acc1.z; a.w = acc0.w + acc1.w;
    #pragma unroll
    for (int m = 8; m < 64; m <<= 1) {
        a.x += __shfl_xor(a.x, m, 64);
        a.y += __shfl_xor(a.y, m, 64);
        a.z += __shfl_xor(a.z, m, 64);
        a.w += __shfl_xor(a.w, m, 64);
    }
    if (es == 0) {
        float4 bv = *(const float4*)&b1[q * 4];
        float dr = dis[r];
        float4 v;
        v.x = dr * a.x + bv.x; v.y = dr * a.y + bv.y; v.z = dr * a.z + bv.z; v.w = dr * a.w + bv.w;
        v.x = v.x > 0.f ? v.x : 0.1f * v.x;
        v.y = v.y > 0.f ? v.y : 0.1f * v.y;
        v.z = v.z > 0.f ? v.z : 0.1f * v.z;
        v.w = v.w > 0.f ? v.w : 0.1f * v.w;
        v.x *= dr; v.y *= dr; v.z *= dr; v.w *= dr;
        storeh8(t1h + (size_t)r * 32 + q * 4, v);   // 8 lanes x 8B = full 64B row
    }
}

// ---------------- agg2 v5: gather-only, fp16 rows, 8 rows/wave pipelined;
//   writes agg32[r] = dis[r]*(sum_neigh t1 + self) in fp32 (coalesced 128B).
//   No W2, no pool, no atomics: those move to gemm2p.
__global__ __launch_bounds__(256) void agg2_kernel(const __half* __restrict__ t1h, const int* __restrict__ colb,
                                                   const int* __restrict__ rowptr, const int* __restrict__ cnt,
                                                   const float* __restrict__ dis,
                                                   float* __restrict__ agg32) {
    const int ROWS = 8;
    int tid = threadIdx.x;
    int wid = tid >> 6;
    int lane = tid & 63;
    int es = lane >> 3;   // edge slot 0..7
    int q = lane & 7;     // feature quad 0..7
    int w = blockIdx.x * 4 + wid;          // 12500 waves exactly
    int r0 = w * ROWS;

    const float2 z2 = make_float2(0.f, 0.f);   // 4x fp16 zeros
    // pre-issue row r0 (raw 8B loads; convert at consume)
    int st = rowptr[r0];
    int n = cnt[r0];
    float2 pS = z2, p0 = z2, p1 = z2, p2 = z2, p3 = z2;
    if (es == 0) pS = *(const float2*)(t1h + (size_t)r0 * 32 + q * 4);
    {
        int e0 = es, e1 = 8 + es, e2 = 16 + es, e3 = 24 + es;
        if (e0 < n) p0 = *(const float2*)(t1h + (size_t)colb[st + e0] * 32 + q * 4);
        if (e1 < n) p1 = *(const float2*)(t1h + (size_t)colb[st + e1] * 32 + q * 4);
        if (e2 < n) p2 = *(const float2*)(t1h + (size_t)colb[st + e2] * 32 + q * 4);
        if (e3 < n) p3 = *(const float2*)(t1h + (size_t)colb[st + e3] * 32 + q * 4);
    }
    for (int i = 0; i < ROWS; i++) {
        int r = r0 + i;
        int stA = st, nA = n;
        float2 rS = pS, r0v = p0, r1v = p1, r2v = p2, r3v = p3;
        // pre-issue row r+1 before consuming row r
        pS = z2; p0 = z2; p1 = z2; p2 = z2; p3 = z2;
        if (i + 1 < ROWS) {
            int rn = r + 1;
            st = rowptr[rn];
            n = cnt[rn];
            if (es == 0) pS = *(const float2*)(t1h + (size_t)rn * 32 + q * 4);
            int e0 = es, e1 = 8 + es, e2 = 16 + es, e3 = 24 + es;
            if (e0 < n) p0 = *(const float2*)(t1h + (size_t)colb[st + e0] * 32 + q * 4);
            if (e1 < n) p1 = *(const float2*)(t1h + (size_t)colb[st + e1] * 32 + q * 4);
            if (e2 < n) p2 = *(const float2*)(t1h + (size_t)colb[st + e2] * 32 + q * 4);
            if (e3 < n) p3 = *(const float2*)(t1h + (size_t)colb[st + e3] * 32 + q * 4);
        }
        // consume row r
        float4 s = cvt8(rS), a0 = cvt8(r0v), a1 = cvt8(r1v), a2 = cvt8(r2v), a3 = cvt8(r3v);
        float4 a;
        a.x = (s.x + (a0.x + a1.x)) + (a2.x + a3.x);
        a.y = (s.y + (a0.y + a1.y)) + (a2.y + a3.y);
        a.z = (s.z + (a0.z + a1.z)) + (a2.z + a3.z);
        a.w = (s.w + (a0.w + a1.w)) + (a2.w + a3.w);
        // rare tail: degree > 32
        for (int k = 32; k < nA; k += 16) {
            int e0 = k + es, e1 = k + 8 + es;
            if (e0 < nA) {
                float4 v = loadh8(t1h + (size_t)colb[stA + e0] * 32 + q * 4);
                a.x += v.x; a.y += v.y; a.z += v.z; a.w += v.w;
            }
            if (e1 < nA) {
                float4 v = loadh8(t1h + (size_t)colb[stA + e1] * 32 + q * 4);
                a.x += v.x; a.y += v.y; a.z += v.z; a.w += v.w;
            }
        }
        #pragma unroll
        for (int m = 8; m < 64; m <<= 1) {
            a.x += __shfl_xor(a.x, m, 64);
            a.y += __shfl_xor(a.y, m, 64);
            a.z += __shfl_xor(a.z, m, 64);
            a.w += __shfl_xor(a.w, m, 64);
        }
        if (es == 0) {
            float dr = dis[r];
            float4 o = make_float4(dr * a.x, dr * a.y, dr * a.z, dr * a.w);
            *(float4*)&agg32[(size_t)r * 32 + q * 4] = o;   // 8 lanes x 16B = 128B row
        }
    }
}

// ---------------- gemm2p: out = agg32 @ W2 + b2, fused global-max-pool ----------------
__global__ __launch_bounds__(256) void gemm2p_kernel(const float* __restrict__ agg32, const float* __restrict__ W2,
                                                     const float* __restrict__ b2, const int* __restrict__ batch,
                                                     unsigned* __restrict__ gbufu) {
    __shared__ float as1[64][32];    // 8 KB
    __shared__ float w2s[32][64];    // 8 KB
    __shared__ float red[4][64];
    int tid = threadIdx.x;
    int r0 = blockIdx.x * 64;
    for (int idx = tid; idx < 32 * 64; idx += 256) w2s[idx >> 6][idx & 63] = W2[idx];
    for (int idx = tid; idx < 64 * 8; idx += 256) {
        int rl = idx >> 3, qc = idx & 7;
        int gr = r0 + rl;
        float4 v = (gr < N_NODES) ? ((const float4*)agg32)[(size_t)gr * 8 + qc] : make_float4(0.f, 0.f, 0.f, 0.f);
        *(float4*)&as1[rl][qc * 4] = v;
    }
    __syncthreads();
    int j = tid & 63;
    int rq = tid >> 6;   // wave id 0..3
    float w2c[32];
    #pragma unroll
    for (int k = 0; k < 32; k++) w2c[k] = w2s[k][j];
    float bj = b2[j];
    int rend = (r0 + 64 <= N_NODES) ? 64 : (N_NODES - r0);
    int gfirst = batch[r0];
    int glast = batch[r0 + rend - 1];
    bool uni = (gfirst == glast);    // block-uniform condition
    float runmax = -INFINITY;
    for (int i = 0; i < 16; i++) {
        int rl = rq + i * 4;
        if (rl >= rend) break;
        float acc = bj;
        #pragma unroll
        for (int kc = 0; kc < 32; kc += 4) {
            float4 av = *(const float4*)&as1[rl][kc];
            acc += av.x * w2c[kc] + av.y * w2c[kc + 1] + av.z * w2c[kc + 2] + av.w * w2c[kc + 3];
        }
        if (uni) runmax = fmaxf(runmax, acc);
        else atomicMax(&gbufu[batch[r0 + rl] * 64 + j], f2o(acc));   // rare boundary blocks
    }
    if (uni) {
        red[rq][j] = runmax;
        __syncthreads();
        if (tid < 64) {
            float m = fmaxf(fmaxf(red[0][tid], red[1][tid]), fmaxf(red[2][tid], red[3][tid]));
            atomicMax(&gbufu[gfirst * 64 + tid], f2o(m));
        }
    }
}

// ---------------- MLP head, single block ----------------
__global__ __launch_bounds__(256) void mlp_kernel(const unsigned* __restrict__ gbufu,
                                                  const float* __restrict__ Wl1, const float* __restrict__ bl1,
                                                  const float* __restrict__ Wl2, const float* __restrict__ bl2,
                                                  const float* __restrict__ Wl3, const float* __restrict__ bl3,
                                                  float* __restrict__ out) {
    __shared__ float A[64][64];
    __shared__ float B[64][128];
    int tid = threadIdx.x;
    for (int idx = tid; idx < 64 * 64; idx += 256) A[idx >> 6][idx & 63] = o2f(gbufu[idx]);
    __syncthreads();
    {
        int j = tid & 127;
        int rg = tid >> 7;
        float wc[64];
        #pragma unroll
        for (int k = 0; k < 64; k++) wc[k] = Wl1[k * 128 + j];
        float bj = bl1[j];
        for (int r = rg; r < 64; r += 2) {
            float acc = bj;
            #pragma unroll
            for (int kc = 0; kc < 64; kc += 4) {
                float4 av = *(const float4*)&A[r][kc];
                acc += av.x * wc[kc] + av.y * wc[kc + 1] + av.z * wc[kc + 2] + av.w * wc[kc + 3];
            }
            B[r][j] = acc > 0.f ? acc : 0.1f * acc;
        }
    }
    __syncthreads();
    {
        int j = tid & 63;
        int rg = tid >> 6;
        float wc[128];
        #pragma unroll
        for (int k = 0; k < 128; k++) wc[k] = Wl2[k * 64 + j];
        float bj = bl2[j];
        for (int r = rg; r < 64; r += 4) {
            float acc = bj;
            #pragma unroll
            for (int kc = 0; kc < 128; kc += 4) {
                float4 bv = *(const float4*)&B[r][kc];
                acc += bv.x * wc[kc] + bv.y * wc[kc + 1] + bv.z * wc[kc + 2] + bv.w * wc[kc + 3];
            }
            A[r][j] = acc > 0.f ? acc : 0.1f * acc;
        }
    }
    __syncthreads();
    if (tid < 64) {
        int r = tid;
        float acc = bl3[0];
        #pragma unroll
        for (int k = 0; k < 64; k++) acc += A[r][k] * Wl3[k];
        out[r] = acc;
    }
}

extern "C" void kernel_launch(void* const* d_in, const int* in_sizes, int n_in,
                              void* d_out, int out_size, void* d_ws, size_t ws_size,
                              hipStream_t stream) {
    (void)in_sizes; (void)n_in; (void)out_size; (void)ws_size;
    const float* x    = (const float*)d_in[0];
    const int*   edge = (const int*)d_in[1];
    const int*   batch= (const int*)d_in[2];
    const float* W1   = (const float*)d_in[3];
    const float* b1   = (const float*)d_in[4];
    const float* W2   = (const float*)d_in[5];
    const float* b2   = (const float*)d_in[6];
    const float* Wl1  = (const float*)d_in[7];
    const float* bl1  = (const float*)d_in[8];
    const float* Wl2  = (const float*)d_in[9];
    const float* bl2  = (const float*)d_in[10];
    const float* Wl3  = (const float*)d_in[11];
    const float* bl3  = (const float*)d_in[12];
    const int* srcp = edge;
    const int* dstp = edge + N_EDGES;

    // workspace layout: zeroed region first = cnt[N] + total[1] + gbufu[64*64] -> one memset
    char* ws = (char*)d_ws;
    int*      cnt   = (int*)ws;
    int*      total = cnt + N_NODES;
    unsigned* gbufu = (unsigned*)(total + 1);
    size_t zeroed = (size_t)(N_NODES + 1 + N_GRAPHS * 64) * 4;
    size_t off = (zeroed + 255) & ~(size_t)255;
    auto alloc = [&](size_t bytes) { char* p = ws + off; off = (off + bytes + 255) & ~(size_t)255; return p; };
    int*    pos    = (int*)alloc((size_t)N_EDGES * 4);
    int*    rowptr = (int*)alloc((size_t)N_NODES * 4);
    float*  dis    = (float*)alloc((size_t)N_NODES * 4);
    int*    colb   = (int*)alloc((size_t)N_EDGES * 4);
    __half* hs1h   = (__half*)alloc((size_t)N_NODES * 32 * 2);
    __half* t1h    = (__half*)alloc((size_t)N_NODES * 32 * 2);
    float*  agg32  = (float*)alloc((size_t)N_NODES * 32 * 4);

    hipMemsetAsync(ws, 0, zeroed, stream);

    deg_kernel   <<<(N_EDGES + 255) / 256, 256, 0, stream>>>(dstp, cnt, pos);
    alloc_kernel <<<(N_NODES + 255) / 256, 256, 0, stream>>>(cnt, dis, rowptr, total);
    fill_kernel  <<<(N_EDGES + 255) / 256, 256, 0, stream>>>(srcp, dstp, rowptr, pos, colb);
    gemm1_kernel <<<(N_NODES + 63) / 64, 256, 0, stream>>>(x, W1, dis, hs1h);
    agg1_kernel  <<<N_NODES / 4, 256, 0, stream>>>(hs1h, colb, rowptr, cnt, dis, b1, t1h);
    agg2_kernel  <<<3125, 256, 0, stream>>>(t1h, colb, rowptr, cnt, dis, agg32);   // 12500 waves x 8 rows
    gemm2p_kernel<<<(N_NODES + 63) / 64, 256, 0, stream>>>(agg32, W2, b2, batch, gbufu);
    mlp_kernel   <<<1, 256, 0, stream>>>(gbufu, Wl1, bl1, Wl2, bl2, Wl3, bl3, (float*)d_out);
}

// Round 8
// 401.930 us; speedup vs baseline: 1.1109x; 1.0024x over previous
//
#include <hip/hip_runtime.h>
#include <hip/hip_fp16.h>
#include <math.h>

#define N_NODES 100000
#define N_EDGES 1600000
#define N_GRAPHS 64

// ordered-uint encode for float atomicMax (monotone bijection)
__device__ __forceinline__ unsigned f2o(float f) {
    unsigned u = __float_as_uint(f);
    return (u & 0x80000000u) ? ~u : (u | 0x80000000u);
}
__device__ __forceinline__ float o2f(unsigned u) {
    return (u & 0x80000000u) ? __uint_as_float(u & 0x7fffffffu) : __uint_as_float(~u);
}

// 8B load of 4 fp16 -> float4
__device__ __forceinline__ float4 cvt8(float2 raw) {
    __half2 h0 = ((const __half2*)&raw)[0];
    __half2 h1 = ((const __half2*)&raw)[1];
    float2 f0 = __half22float2(h0);
    float2 f1 = __half22float2(h1);
    return make_float4(f0.x, f0.y, f1.x, f1.y);
}
__device__ __forceinline__ float4 loadh8(const __half* p) {
    return cvt8(*(const float2*)p);
}
__device__ __forceinline__ void storeh8(__half* p, float4 v) {
    __half2 o0 = __floats2half2_rn(v.x, v.y);
    __half2 o1 = __floats2half2_rn(v.z, v.w);
    float2 ow;
    ((__half2*)&ow)[0] = o0;
    ((__half2*)&ow)[1] = o1;
    *(float2*)p = ow;
}

// ---------------- degree count + per-edge slot, 4 edges/thread (atomic ILP) ----------------
__global__ __launch_bounds__(256) void deg_kernel(const int* __restrict__ dst, int* __restrict__ cnt,
                                                  int* __restrict__ pos) {
    int e = (blockIdx.x * 256 + threadIdx.x) * 4;
    if (e >= N_EDGES) return;           // N_EDGES % 4 == 0: all-or-nothing per thread
    int4 d = *(const int4*)(dst + e);
    int p0 = atomicAdd(&cnt[d.x], 1);   // 4 independent atomics in flight
    int p1 = atomicAdd(&cnt[d.y], 1);
    int p2 = atomicAdd(&cnt[d.z], 1);
    int p3 = atomicAdd(&cnt[d.w], 1);
    *(int4*)(pos + e) = make_int4(p0, p1, p2, p3);
}

// ---------------- dis + row allocation (wave scan) ----------------
__global__ __launch_bounds__(256) void alloc_kernel(const int* __restrict__ cnt,
                                                    float* __restrict__ dis, int* __restrict__ rowptr,
                                                    int* __restrict__ total) {
    int i = blockIdx.x * 256 + threadIdx.x;
    int c = (i < N_NODES) ? cnt[i] : 0;
    if (i < N_NODES) dis[i] = rsqrtf((float)(c + 1));
    int lane = threadIdx.x & 63;
    int s = c;
    #pragma unroll
    for (int o = 1; o < 64; o <<= 1) {
        int v = __shfl_up(s, o, 64);
        if (lane >= o) s += v;
    }
    int wtot = __shfl(s, 63, 64);
    int base = 0;
    if (lane == 0) base = atomicAdd(total, wtot);
    base = __shfl(base, 0, 64);
    if (i < N_NODES) rowptr[i] = base + s - c;   // exclusive within wave
}

// ---------------- CSR fill, 4 edges/thread (gather+scatter ILP) ----------------
__global__ __launch_bounds__(256) void fill_kernel(const int* __restrict__ src, const int* __restrict__ dst,
                                                   const int* __restrict__ rowptr, const int* __restrict__ pos,
                                                   int* __restrict__ colb) {
    int e = (blockIdx.x * 256 + threadIdx.x) * 4;
    if (e >= N_EDGES) return;
    int4 s = *(const int4*)(src + e);
    int4 d = *(const int4*)(dst + e);
    int4 p = *(const int4*)(pos + e);
    int r0 = rowptr[d.x];               // 4 independent gathers
    int r1 = rowptr[d.y];
    int r2 = rowptr[d.z];
    int r3 = rowptr[d.w];
    __builtin_nontemporal_store(s.x, &colb[r0 + p.x]);
    __builtin_nontemporal_store(s.y, &colb[r1 + p.y]);
    __builtin_nontemporal_store(s.z, &colb[r2 + p.z]);
    __builtin_nontemporal_store(s.w, &colb[r3 + p.w]);
}

// ---------------- GEMM1: hs1h = fp16(dis * (x @ W1)), [N,128]x[128,32] ----------------
__global__ __launch_bounds__(256) void gemm1_kernel(const float* __restrict__ x, const float* __restrict__ W1,
                                                    const float* __restrict__ dis, __half* __restrict__ hs1h) {
    __shared__ float xs[64][128];     // 32 KB
    __shared__ float wt[32][132];     // W1^T padded
    int tid = threadIdx.x;
    int r0 = blockIdx.x * 64;
    for (int idx = tid; idx < 128 * 32; idx += 256) {
        int k = idx >> 5, j = idx & 31;
        wt[j][k] = W1[idx];
    }
    for (int idx = tid; idx < 64 * 32; idx += 256) {
        int r = idx >> 5, kc = idx & 31;
        int gr = r0 + r;
        float4 v = (gr < N_NODES) ? ((const float4*)x)[(size_t)gr * 32 + kc] : make_float4(0.f, 0.f, 0.f, 0.f);
        *(float4*)&xs[r][kc * 4] = v;
    }
    __syncthreads();
    int j = tid & 31;
    int rr = tid >> 5;   // 0..7
    float acc[8];
    #pragma unroll
    for (int i = 0; i < 8; i++) acc[i] = 0.f;
    for (int kc = 0; kc < 128; kc += 4) {
        float4 wv = *(const float4*)&wt[j][kc];
        #pragma unroll
        for (int i = 0; i < 8; i++) {
            float4 xv = *(const float4*)&xs[rr + i * 8][kc];
            acc[i] += xv.x * wv.x + xv.y * wv.y + xv.z * wv.z + xv.w * wv.w;
        }
    }
    #pragma unroll
    for (int i = 0; i < 8; i++) {
        int gr = r0 + rr + i * 8;
        if (gr < N_NODES) hs1h[(size_t)gr * 32 + j] = __float2half_rn(dis[gr] * acc[i]);
    }
}

// ---------------- agg1 v2: 8 rows/wave, 2-stage pipeline over fp16 rows;
//   t1h[r] = fp16( dis[r] * lrelu(dis[r]*(sum_neigh hs1 + self) + b1) )
__global__ __launch_bounds__(256) void agg1_kernel(const __half* __restrict__ hs1h, const int* __restrict__ colb,
                                                   const int* __restrict__ rowptr, const int* __restrict__ cnt,
                                                   const float* __restrict__ dis, const float* __restrict__ b1,
                                                   __half* __restrict__ t1h) {
    const int ROWS = 8;
    int tid = threadIdx.x;
    int wid = tid >> 6;
    int lane = tid & 63;
    int es = lane >> 3;   // edge slot 0..7
    int q = lane & 7;     // feature quad 0..7
    int w = blockIdx.x * 4 + wid;          // 12500 waves exactly
    int r0 = w * ROWS;

    const float2 z2 = make_float2(0.f, 0.f);
    int st = rowptr[r0];
    int n = cnt[r0];
    float2 pS = z2, p0 = z2, p1 = z2, p2 = z2, p3 = z2;
    if (es == 0) pS = *(const float2*)(hs1h + (size_t)r0 * 32 + q * 4);
    {
        int e0 = es, e1 = 8 + es, e2 = 16 + es, e3 = 24 + es;
        if (e0 < n) p0 = *(const float2*)(hs1h + (size_t)colb[st + e0] * 32 + q * 4);
        if (e1 < n) p1 = *(const float2*)(hs1h + (size_t)colb[st + e1] * 32 + q * 4);
        if (e2 < n) p2 = *(const float2*)(hs1h + (size_t)colb[st + e2] * 32 + q * 4);
        if (e3 < n) p3 = *(const float2*)(hs1h + (size_t)colb[st + e3] * 32 + q * 4);
    }
    for (int i = 0; i < ROWS; i++) {
        int r = r0 + i;
        int stA = st, nA = n;
        float2 rS = pS, r0v = p0, r1v = p1, r2v = p2, r3v = p3;
        pS = z2; p0 = z2; p1 = z2; p2 = z2; p3 = z2;
        if (i + 1 < ROWS) {
            int rn = r + 1;
            st = rowptr[rn];
            n = cnt[rn];
            if (es == 0) pS = *(const float2*)(hs1h + (size_t)rn * 32 + q * 4);
            int e0 = es, e1 = 8 + es, e2 = 16 + es, e3 = 24 + es;
            if (e0 < n) p0 = *(const float2*)(hs1h + (size_t)colb[st + e0] * 32 + q * 4);
            if (e1 < n) p1 = *(const float2*)(hs1h + (size_t)colb[st + e1] * 32 + q * 4);
            if (e2 < n) p2 = *(const float2*)(hs1h + (size_t)colb[st + e2] * 32 + q * 4);
            if (e3 < n) p3 = *(const float2*)(hs1h + (size_t)colb[st + e3] * 32 + q * 4);
        }
        float4 s = cvt8(rS), a0 = cvt8(r0v), a1 = cvt8(r1v), a2 = cvt8(r2v), a3 = cvt8(r3v);
        float4 a;
        a.x = (s.x + (a0.x + a1.x)) + (a2.x + a3.x);
        a.y = (s.y + (a0.y + a1.y)) + (a2.y + a3.y);
        a.z = (s.z + (a0.z + a1.z)) + (a2.z + a3.z);
        a.w = (s.w + (a0.w + a1.w)) + (a2.w + a3.w);
        for (int k = 32; k < nA; k += 16) {     // rare tail: degree > 32
            int e0 = k + es, e1 = k + 8 + es;
            if (e0 < nA) {
                float4 v = loadh8(hs1h + (size_t)colb[stA + e0] * 32 + q * 4);
                a.x += v.x; a.y += v.y; a.z += v.z; a.w += v.w;
            }
            if (e1 < nA) {
                float4 v = loadh8(hs1h + (size_t)colb[stA + e1] * 32 + q * 4);
                a.x += v.x; a.y += v.y; a.z += v.z; a.w += v.w;
            }
        }
        #pragma unroll
        for (int m = 8; m < 64; m <<= 1) {
            a.x += __shfl_xor(a.x, m, 64);
            a.y += __shfl_xor(a.y, m, 64);
            a.z += __shfl_xor(a.z, m, 64);
            a.w += __shfl_xor(a.w, m, 64);
        }
        if (es == 0) {
            float4 bv = *(const float4*)&b1[q * 4];
            float dr = dis[r];
            float4 v;
            v.x = dr * a.x + bv.x; v.y = dr * a.y + bv.y; v.z = dr * a.z + bv.z; v.w = dr * a.w + bv.w;
            v.x = v.x > 0.f ? v.x : 0.1f * v.x;
            v.y = v.y > 0.f ? v.y : 0.1f * v.y;
            v.z = v.z > 0.f ? v.z : 0.1f * v.z;
            v.w = v.w > 0.f ? v.w : 0.1f * v.w;
            v.x *= dr; v.y *= dr; v.z *= dr; v.w *= dr;
            storeh8(t1h + (size_t)r * 32 + q * 4, v);
        }
    }
}

// ---------------- agg2 v5: gather-only, fp16 rows, 8 rows/wave pipelined;
//   writes agg32[r] = dis[r]*(sum_neigh t1 + self) in fp32 (coalesced 128B).
__global__ __launch_bounds__(256) void agg2_kernel(const __half* __restrict__ t1h, const int* __restrict__ colb,
                                                   const int* __restrict__ rowptr, const int* __restrict__ cnt,
                                                   const float* __restrict__ dis,
                                                   float* __restrict__ agg32) {
    const int ROWS = 8;
    int tid = threadIdx.x;
    int wid = tid >> 6;
    int lane = tid & 63;
    int es = lane >> 3;   // edge slot 0..7
    int q = lane & 7;     // feature quad 0..7
    int w = blockIdx.x * 4 + wid;          // 12500 waves exactly
    int r0 = w * ROWS;

    const float2 z2 = make_float2(0.f, 0.f);
    int st = rowptr[r0];
    int n = cnt[r0];
    float2 pS = z2, p0 = z2, p1 = z2, p2 = z2, p3 = z2;
    if (es == 0) pS = *(const float2*)(t1h + (size_t)r0 * 32 + q * 4);
    {
        int e0 = es, e1 = 8 + es, e2 = 16 + es, e3 = 24 + es;
        if (e0 < n) p0 = *(const float2*)(t1h + (size_t)colb[st + e0] * 32 + q * 4);
        if (e1 < n) p1 = *(const float2*)(t1h + (size_t)colb[st + e1] * 32 + q * 4);
        if (e2 < n) p2 = *(const float2*)(t1h + (size_t)colb[st + e2] * 32 + q * 4);
        if (e3 < n) p3 = *(const float2*)(t1h + (size_t)colb[st + e3] * 32 + q * 4);
    }
    for (int i = 0; i < ROWS; i++) {
        int r = r0 + i;
        int stA = st, nA = n;
        float2 rS = pS, r0v = p0, r1v = p1, r2v = p2, r3v = p3;
        pS = z2; p0 = z2; p1 = z2; p2 = z2; p3 = z2;
        if (i + 1 < ROWS) {
            int rn = r + 1;
            st = rowptr[rn];
            n = cnt[rn];
            if (es == 0) pS = *(const float2*)(t1h + (size_t)rn * 32 + q * 4);
            int e0 = es, e1 = 8 + es, e2 = 16 + es, e3 = 24 + es;
            if (e0 < n) p0 = *(const float2*)(t1h + (size_t)colb[st + e0] * 32 + q * 4);
            if (e1 < n) p1 = *(const float2*)(t1h + (size_t)colb[st + e1] * 32 + q * 4);
            if (e2 < n) p2 = *(const float2*)(t1h + (size_t)colb[st + e2] * 32 + q * 4);
            if (e3 < n) p3 = *(const float2*)(t1h + (size_t)colb[st + e3] * 32 + q * 4);
        }
        float4 s = cvt8(rS), a0 = cvt8(r0v), a1 = cvt8(r1v), a2 = cvt8(r2v), a3 = cvt8(r3v);
        float4 a;
        a.x = (s.x + (a0.x + a1.x)) + (a2.x + a3.x);
        a.y = (s.y + (a0.y + a1.y)) + (a2.y + a3.y);
        a.z = (s.z + (a0.z + a1.z)) + (a2.z + a3.z);
        a.w = (s.w + (a0.w + a1.w)) + (a2.w + a3.w);
        for (int k = 32; k < nA; k += 16) {     // rare tail: degree > 32
            int e0 = k + es, e1 = k + 8 + es;
            if (e0 < nA) {
                float4 v = loadh8(t1h + (size_t)colb[stA + e0] * 32 + q * 4);
                a.x += v.x; a.y += v.y; a.z += v.z; a.w += v.w;
            }
            if (e1 < nA) {
                float4 v = loadh8(t1h + (size_t)colb[stA + e1] * 32 + q * 4);
                a.x += v.x; a.y += v.y; a.z += v.z; a.w += v.w;
            }
        }
        #pragma unroll
        for (int m = 8; m < 64; m <<= 1) {
            a.x += __shfl_xor(a.x, m, 64);
            a.y += __shfl_xor(a.y, m, 64);
            a.z += __shfl_xor(a.z, m, 64);
            a.w += __shfl_xor(a.w, m, 64);
        }
        if (es == 0) {
            float dr = dis[r];
            float4 o = make_float4(dr * a.x, dr * a.y, dr * a.z, dr * a.w);
            *(float4*)&agg32[(size_t)r * 32 + q * 4] = o;
        }
    }
}

// ---------------- gemm2p: out = agg32 @ W2 + b2, fused global-max-pool ----------------
__global__ __launch_bounds__(256) void gemm2p_kernel(const float* __restrict__ agg32, const float* __restrict__ W2,
                                                     const float* __restrict__ b2, const int* __restrict__ batch,
                                                     unsigned* __restrict__ gbufu) {
    __shared__ float as1[64][32];    // 8 KB
    __shared__ float w2s[32][64];    // 8 KB
    __shared__ float red[4][64];
    int tid = threadIdx.x;
    int r0 = blockIdx.x * 64;
    for (int idx = tid; idx < 32 * 64; idx += 256) w2s[idx >> 6][idx & 63] = W2[idx];
    for (int idx = tid; idx < 64 * 8; idx += 256) {
        int rl = idx >> 3, qc = idx & 7;
        int gr = r0 + rl;
        float4 v = (gr < N_NODES) ? ((const float4*)agg32)[(size_t)gr * 8 + qc] : make_float4(0.f, 0.f, 0.f, 0.f);
        *(float4*)&as1[rl][qc * 4] = v;
    }
    __syncthreads();
    int j = tid & 63;
    int rq = tid >> 6;   // wave id 0..3
    float w2c[32];
    #pragma unroll
    for (int k = 0; k < 32; k++) w2c[k] = w2s[k][j];
    float bj = b2[j];
    int rend = (r0 + 64 <= N_NODES) ? 64 : (N_NODES - r0);
    int gfirst = batch[r0];
    int glast = batch[r0 + rend - 1];
    bool uni = (gfirst == glast);    // block-uniform condition
    float runmax = -INFINITY;
    for (int i = 0; i < 16; i++) {
        int rl = rq + i * 4;
        if (rl >= rend) break;
        float acc = bj;
        #pragma unroll
        for (int kc = 0; kc < 32; kc += 4) {
            float4 av = *(const float4*)&as1[rl][kc];
            acc += av.x * w2c[kc] + av.y * w2c[kc + 1] + av.z * w2c[kc + 2] + av.w * w2c[kc + 3];
        }
        if (uni) runmax = fmaxf(runmax, acc);
        else atomicMax(&gbufu[batch[r0 + rl] * 64 + j], f2o(acc));   // rare boundary blocks
    }
    if (uni) {
        red[rq][j] = runmax;
        __syncthreads();
        if (tid < 64) {
            float m = fmaxf(fmaxf(red[0][tid], red[1][tid]), fmaxf(red[2][tid], red[3][tid]));
            atomicMax(&gbufu[gfirst * 64 + tid], f2o(m));
        }
    }
}

// ---------------- MLP head, single block ----------------
__global__ __launch_bounds__(256) void mlp_kernel(const unsigned* __restrict__ gbufu,
                                                  const float* __restrict__ Wl1, const float* __restrict__ bl1,
                                                  const float* __restrict__ Wl2, const float* __restrict__ bl2,
                                                  const float* __restrict__ Wl3, const float* __restrict__ bl3,
                                                  float* __restrict__ out) {
    __shared__ float A[64][64];
    __shared__ float B[64][128];
    int tid = threadIdx.x;
    for (int idx = tid; idx < 64 * 64; idx += 256) A[idx >> 6][idx & 63] = o2f(gbufu[idx]);
    __syncthreads();
    {
        int j = tid & 127;
        int rg = tid >> 7;
        float wc[64];
        #pragma unroll
        for (int k = 0; k < 64; k++) wc[k] = Wl1[k * 128 + j];
        float bj = bl1[j];
        for (int r = rg; r < 64; r += 2) {
            float acc = bj;
            #pragma unroll
            for (int kc = 0; kc < 64; kc += 4) {
                float4 av = *(const float4*)&A[r][kc];
                acc += av.x * wc[kc] + av.y * wc[kc + 1] + av.z * wc[kc + 2] + av.w * wc[kc + 3];
            }
            B[r][j] = acc > 0.f ? acc : 0.1f * acc;
        }
    }
    __syncthreads();
    {
        int j = tid & 63;
        int rg = tid >> 6;
        float wc[128];
        #pragma unroll
        for (int k = 0; k < 128; k++) wc[k] = Wl2[k * 64 + j];
        float bj = bl2[j];
        for (int r = rg; r < 64; r += 4) {
            float acc = bj;
            #pragma unroll
            for (int kc = 0; kc < 128; kc += 4) {
                float4 bv = *(const float4*)&B[r][kc];
                acc += bv.x * wc[kc] + bv.y * wc[kc + 1] + bv.z * wc[kc + 2] + bv.w * wc[kc + 3];
            }
            A[r][j] = acc > 0.f ? acc : 0.1f * acc;
        }
    }
    __syncthreads();
    if (tid < 64) {
        int r = tid;
        float acc = bl3[0];
        #pragma unroll
        for (int k = 0; k < 64; k++) acc += A[r][k] * Wl3[k];
        out[r] = acc;
    }
}

extern "C" void kernel_launch(void* const* d_in, const int* in_sizes, int n_in,
                              void* d_out, int out_size, void* d_ws, size_t ws_size,
                              hipStream_t stream) {
    (void)in_sizes; (void)n_in; (void)out_size; (void)ws_size;
    const float* x    = (const float*)d_in[0];
    const int*   edge = (const int*)d_in[1];
    const int*   batch= (const int*)d_in[2];
    const float* W1   = (const float*)d_in[3];
    const float* b1   = (const float*)d_in[4];
    const float* W2   = (const float*)d_in[5];
    const float* b2   = (const float*)d_in[6];
    const float* Wl1  = (const float*)d_in[7];
    const float* bl1  = (const float*)d_in[8];
    const float* Wl2  = (const float*)d_in[9];
    const float* bl2  = (const float*)d_in[10];
    const float* Wl3  = (const float*)d_in[11];
    const float* bl3  = (const float*)d_in[12];
    const int* srcp = edge;
    const int* dstp = edge + N_EDGES;

    // workspace layout: zeroed region first = cnt[N] + total[1] + gbufu[64*64] -> one memset
    char* ws = (char*)d_ws;
    int*      cnt   = (int*)ws;
    int*      total = cnt + N_NODES;
    unsigned* gbufu = (unsigned*)(total + 1);
    size_t zeroed = (size_t)(N_NODES + 1 + N_GRAPHS * 64) * 4;
    size_t off = (zeroed + 255) & ~(size_t)255;
    auto alloc = [&](size_t bytes) { char* p = ws + off; off = (off + bytes + 255) & ~(size_t)255; return p; };
    int*    pos    = (int*)alloc((size_t)N_EDGES * 4);
    int*    rowptr = (int*)alloc((size_t)N_NODES * 4);
    float*  dis    = (float*)alloc((size_t)N_NODES * 4);
    int*    colb   = (int*)alloc((size_t)N_EDGES * 4);
    __half* hs1h   = (__half*)alloc((size_t)N_NODES * 32 * 2);
    __half* t1h    = (__half*)alloc((size_t)N_NODES * 32 * 2);
    float*  agg32  = (float*)alloc((size_t)N_NODES * 32 * 4);

    hipMemsetAsync(ws, 0, zeroed, stream);

    deg_kernel   <<<(N_EDGES / 4 + 255) / 256, 256, 0, stream>>>(dstp, cnt, pos);
    alloc_kernel <<<(N_NODES + 255) / 256, 256, 0, stream>>>(cnt, dis, rowptr, total);
    fill_kernel  <<<(N_EDGES / 4 + 255) / 256, 256, 0, stream>>>(srcp, dstp, rowptr, pos, colb);
    gemm1_kernel <<<(N_NODES + 63) / 64, 256, 0, stream>>>(x, W1, dis, hs1h);
    agg1_kernel  <<<3125, 256, 0, stream>>>(hs1h, colb, rowptr, cnt, dis, b1, t1h);      // 12500 waves x 8 rows
    agg2_kernel  <<<3125, 256, 0, stream>>>(t1h, colb, rowptr, cnt, dis, agg32);         // 12500 waves x 8 rows
    gemm2p_kernel<<<(N_NODES + 63) / 64, 256, 0, stream>>>(agg32, W2, b2, batch, gbufu);
    mlp_kernel   <<<1, 256, 0, stream>>>(gbufu, Wl1, bl1, Wl2, bl2, Wl3, bl3, (float*)d_out);
}